// Round 1
// baseline (105.567 us; speedup 1.0000x reference)
//
#include <hip/hip_runtime.h>
#include <math.h>

#define TILE  512
#define BLOCK 256
#define NC    128

__device__ __forceinline__ unsigned enc_f(float f) {
    unsigned u = __float_as_uint(f);
    return (u & 0x80000000u) ? ~u : (u | 0x80000000u);
}
__device__ __forceinline__ float dec_f(unsigned e) {
    unsigned v = (e & 0x80000000u) ? (e & 0x7FFFFFFFu) : ~e;
    return __uint_as_float(v);
}

// Init: set per-corner min slots to +max-encoding, and compute camera scalars
// (rotation matrix, focal, principal point) ONCE in double precision.
__global__ void init_kernel(const float* __restrict__ theta,
                            const float* __restrict__ vang,
                            const int* __restrict__ hh,
                            const int* __restrict__ ww,
                            float* __restrict__ scal,
                            unsigned* __restrict__ mins) {
    int t = threadIdx.x;
    if (t < NC) mins[t] = 0xFFFFFFFFu;
    if (t == 0) {
        const double D2R = 0.017453292519943295;
        double a = (double)theta[0] * D2R;
        double b = (double)theta[1] * D2R;
        double c = (double)theta[2] * D2R;
        double sa = sin(a), ca = cos(a);
        double sb = sin(b), cb = cos(b);
        double sc = sin(c), cc = cos(c);
        double H = (double)hh[0], W = (double)ww[0];
        double fd = -H / (2.0 * tan((double)vang[0] * 0.5 * D2R));
        // R = Rz @ Ry @ Rx
        scal[0] = (float)(cc * cb);
        scal[1] = (float)(cc * sb * sa - sc * ca);
        scal[2] = (float)(cc * sb * ca + sc * sa);
        scal[3] = (float)(sc * cb);
        scal[4] = (float)(sc * sb * sa + cc * ca);
        scal[5] = (float)(sc * sb * ca - cc * sa);
        scal[6] = (float)(-sb);
        scal[7] = (float)(cb * sa);
        scal[8] = (float)(cb * ca);
        scal[9]  = (float)fd;                 // f
        scal[10] = (float)(W * 0.5 - 0.5);    // cx
        scal[11] = (float)(H * 0.5 + 0.5);    // H - cy  (v-flip offset)
    }
}

// One block per 512-point tile. Phase 1: project points -> LDS (u, vflip, b2).
// Phase 2: lane owns 2 corners (in regs), streams tile from LDS (broadcast
// reads: all lanes of a wave read the same float4), tracks running minima.
__global__ __launch_bounds__(BLOCK) void proj_min_kernel(
        const float* __restrict__ pnt,
        const float* __restrict__ cor,
        const float* __restrict__ cam,
        const float* __restrict__ scal,
        unsigned* __restrict__ mins,
        int n) {
    __shared__ float4 uvb[TILE];
    __shared__ float red[2 * BLOCK];

    const int tid = threadIdx.x;
    const float r00 = scal[0], r01 = scal[1], r02 = scal[2];
    const float r10 = scal[3], r11 = scal[4], r12 = scal[5];
    const float r20 = scal[6], r21 = scal[7], r22 = scal[8];
    const float f = scal[9], cx = scal[10], cyv = scal[11];
    const float c0 = cam[0], c1 = cam[1], c2 = cam[2];

    const int base = blockIdx.x * TILE;

    #pragma unroll
    for (int k = 0; k < TILE; k += BLOCK) {
        int i = base + k + tid;
        float u = 0.f, vf = 0.f, b2 = 3.0e38f;  // masked points -> never min
        if (i < n) {
            float px = pnt[3 * i], py = pnt[3 * i + 1], pz = pnt[3 * i + 2];
            float tx = px - c0, ty = py - c1, tz = pz - c2;
            float x = fmaf(r00, tx, fmaf(r01, ty, r02 * tz));
            float y = fmaf(r10, tx, fmaf(r11, ty, r12 * tz));
            float z = fmaf(r20, tx, fmaf(r21, ty, r22 * tz));
            float xz = x / z, yz = y / z;     // match reference's true divide
            u  = fmaf(f, xz, cx);
            vf = fmaf(-f, yz, cyv);           // H - (f*y/z + cy)
            b2 = fmaf(u, u, vf * vf);
        }
        uvb[k + tid] = make_float4(u, vf, b2, 0.f);
    }
    __syncthreads();

    const int lane = tid & 63;     // corner pair owner within wave
    const int rep  = tid >> 6;     // wave id = replica, scans 1/4 of tile
    const int ci0 = 2 * lane, ci1 = ci0 + 1;
    const float ax0 = cor[2 * ci0], ay0 = cor[2 * ci0 + 1];
    const float ax1 = cor[2 * ci1], ay1 = cor[2 * ci1 + 1];
    const float a20 = fmaf(ax0, ax0, ay0 * ay0);
    const float a21 = fmaf(ax1, ax1, ay1 * ay1);

    float m0 = 3.4e38f, m1 = 3.4e38f;
    const int p0 = rep * (TILE / 4);
    #pragma unroll 8
    for (int j = 0; j < TILE / 4; ++j) {
        float4 q = uvb[p0 + j];    // broadcast within wave
        float t0 = fmaf(ax0, q.x, ay0 * q.y);
        float d0 = fmaf(-2.f, t0, a20 + q.z);
        m0 = fminf(m0, d0);
        float t1 = fmaf(ax1, q.x, ay1 * q.y);
        float d1 = fmaf(-2.f, t1, a21 + q.z);
        m1 = fminf(m1, d1);
    }

    red[tid] = m0;
    red[BLOCK + tid] = m1;
    __syncthreads();
    if (tid < 64) {
        float mm0 = fminf(fminf(red[tid], red[tid + 64]),
                          fminf(red[tid + 128], red[tid + 192]));
        float mm1 = fminf(fminf(red[BLOCK + tid], red[BLOCK + tid + 64]),
                          fminf(red[BLOCK + tid + 128], red[BLOCK + tid + 192]));
        atomicMin(&mins[ci0], enc_f(mm0));
        atomicMin(&mins[ci1], enc_f(mm1));
    }
}

__global__ void sum_kernel(const unsigned* __restrict__ mins,
                           float* __restrict__ out) {
    __shared__ float s[2];
    int t = threadIdx.x;  // 128 threads
    float v = dec_f(mins[t]);
    #pragma unroll
    for (int off = 32; off > 0; off >>= 1)
        v += __shfl_down(v, off, 64);
    if ((t & 63) == 0) s[t >> 6] = v;
    __syncthreads();
    if (t == 0) out[0] = s[0] + s[1];
}

extern "C" void kernel_launch(void* const* d_in, const int* in_sizes, int n_in,
                              void* d_out, int out_size, void* d_ws, size_t ws_size,
                              hipStream_t stream) {
    const float* pnt   = (const float*)d_in[0];  // (400000,3)
    const float* cor   = (const float*)d_in[1];  // (128,2)
    const float* cam   = (const float*)d_in[2];  // (3,)
    const float* theta = (const float*)d_in[3];  // (3,)
    const float* vang  = (const float*)d_in[4];  // (1,)
    const int*   hh    = (const int*)d_in[5];    // scalar int
    const int*   ww    = (const int*)d_in[6];    // scalar int

    int n = in_sizes[0] / 3;
    float*    scal = (float*)d_ws;                       // 12 floats
    unsigned* mins = (unsigned*)((char*)d_ws + 64);      // 128 slots

    int tiles = (n + TILE - 1) / TILE;
    init_kernel<<<1, 128, 0, stream>>>(theta, vang, hh, ww, scal, mins);
    proj_min_kernel<<<tiles, BLOCK, 0, stream>>>(pnt, cor, cam, scal, mins, n);
    sum_kernel<<<1, 128, 0, stream>>>(mins, (float*)d_out);
}

// Round 2
// 80.522 us; speedup vs baseline: 1.3110x; 1.3110x over previous
//
#include <hip/hip_runtime.h>
#include <math.h>

#define TILE  512
#define BLOCK 256
#define NC    128

// ws layout: scal (12 floats) at +0 ; pbmin (NC * NB floats) at +256.

// Init: compute camera scalars ONCE in double precision (bit-matched the np
// reference in R1: absmax 0.0), and zero the output accumulator.
__global__ void init_kernel(const float* __restrict__ theta,
                            const float* __restrict__ vang,
                            const int* __restrict__ hh,
                            const int* __restrict__ ww,
                            float* __restrict__ scal,
                            float* __restrict__ out) {
    if (threadIdx.x == 0) {
        const double D2R = 0.017453292519943295;
        double a = (double)theta[0] * D2R;
        double b = (double)theta[1] * D2R;
        double c = (double)theta[2] * D2R;
        double sa = sin(a), ca = cos(a);
        double sb = sin(b), cb = cos(b);
        double sc = sin(c), cc = cos(c);
        double H = (double)hh[0], W = (double)ww[0];
        double fd = -H / (2.0 * tan((double)vang[0] * 0.5 * D2R));
        // R = Rz @ Ry @ Rx
        scal[0] = (float)(cc * cb);
        scal[1] = (float)(cc * sb * sa - sc * ca);
        scal[2] = (float)(cc * sb * ca + sc * sa);
        scal[3] = (float)(sc * cb);
        scal[4] = (float)(sc * sb * sa + cc * ca);
        scal[5] = (float)(sc * sb * ca - cc * sa);
        scal[6] = (float)(-sb);
        scal[7] = (float)(cb * sa);
        scal[8] = (float)(cb * ca);
        scal[9]  = (float)fd;                 // f
        scal[10] = (float)(W * 0.5 - 0.5);    // cx
        scal[11] = (float)(H * 0.5 + 0.5);    // H - cy (v-flip offset)
        out[0] = 0.0f;                        // harness poisons d_out; K3 atomicAdds
    }
}

// One block per 512-point tile.
// Phase 1: project tile -> LDS as (u, v_flipped, ||b||^2, 0).
// Phase 2: each lane owns 4 corners (folded consts -2ax,-2ay in regs); the
// wave's two 32-lane halves scan disjoint 64-point ranges, so one broadcast
// ds_read_b128 feeds 2 points (2-way bank aliasing = free). 3 VALU per pair.
// Block minima are STORED (no atomics) to pbmin[corner][block].
__global__ __launch_bounds__(BLOCK) void proj_min_kernel(
        const float* __restrict__ pnt,
        const float* __restrict__ cor,
        const float* __restrict__ cam,
        const float* __restrict__ scal,
        float* __restrict__ pbmin,
        int n, int NB) {
    __shared__ float4 uvb[TILE];
    __shared__ float red[4 * NC];   // [wave][corner]

    const int tid = threadIdx.x;
    const float r00 = scal[0], r01 = scal[1], r02 = scal[2];
    const float r10 = scal[3], r11 = scal[4], r12 = scal[5];
    const float r20 = scal[6], r21 = scal[7], r22 = scal[8];
    const float f = scal[9], cx = scal[10], cyv = scal[11];
    const float c0 = cam[0], c1 = cam[1], c2 = cam[2];

    const int base = blockIdx.x * TILE;

    #pragma unroll
    for (int k = 0; k < TILE; k += BLOCK) {
        int i = base + k + tid;
        float u = 0.f, vf = 0.f, b2 = 3.0e38f;   // masked points never win min
        if (i < n) {
            float px = pnt[3 * i], py = pnt[3 * i + 1], pz = pnt[3 * i + 2];
            float tx = px - c0, ty = py - c1, tz = pz - c2;
            float x = fmaf(r00, tx, fmaf(r01, ty, r02 * tz));
            float y = fmaf(r10, tx, fmaf(r11, ty, r12 * tz));
            float z = fmaf(r20, tx, fmaf(r21, ty, r22 * tz));
            float xz = x / z, yz = y / z;        // match reference's true divide
            u  = fmaf(f, xz, cx);
            vf = fmaf(-f, yz, cyv);              // H - (f*y/z + cy)
            b2 = fmaf(u, u, vf * vf);
        }
        uvb[k + tid] = make_float4(u, vf, b2, 0.f);
    }
    __syncthreads();

    const int lane = tid & 63;
    const int w    = tid >> 6;        // wave id
    const int h    = lane >> 5;       // half-wave: which 64-point subrange
    const int sl   = lane & 31;
    const int cb   = sl << 2;         // this lane's 4 corners: cb..cb+3

    float bx[4], by[4], m[4];
    #pragma unroll
    for (int k = 0; k < 4; ++k) {
        bx[k] = -2.f * cor[2 * (cb + k)];
        by[k] = -2.f * cor[2 * (cb + k) + 1];
        m[k]  = 3.4e38f;
    }

    const float4* p = &uvb[(w << 7) + (h << 6)];
    #pragma unroll 8
    for (int j = 0; j < 64; ++j) {
        float4 q = p[j];              // 2-way broadcast within wave
        #pragma unroll
        for (int k = 0; k < 4; ++k)
            m[k] = fminf(m[k], fmaf(bx[k], q.x, fmaf(by[k], q.y, q.z)));
    }

    // fold the two half-wave scans
    #pragma unroll
    for (int k = 0; k < 4; ++k)
        m[k] = fminf(m[k], __shfl_xor(m[k], 32));
    if (lane < 32) {
        #pragma unroll
        for (int k = 0; k < 4; ++k)
            red[w * NC + cb + k] = m[k];
    }
    __syncthreads();

    if (tid < NC) {   // cross-wave min, then store per-block minimum
        float mm = fminf(fminf(red[tid], red[NC + tid]),
                         fminf(red[2 * NC + tid], red[3 * NC + tid]));
        pbmin[tid * NB + blockIdx.x] = mm;
    }
}

// One block per corner: coalesced row min over NB block-minima, add ||a||^2,
// accumulate into out[0] (128 uncontended atomicAdds).
__global__ void reduce_kernel(const float* __restrict__ pbmin,
                              const float* __restrict__ cor,
                              float* __restrict__ out, int NB) {
    const int c = blockIdx.x;
    const int t = threadIdx.x;        // 64 threads
    const float* row = pbmin + c * NB;
    float m = 3.4e38f;
    for (int i = t; i < NB; i += 64) m = fminf(m, row[i]);
    #pragma unroll
    for (int off = 32; off > 0; off >>= 1)
        m = fminf(m, __shfl_down(m, off));
    if (t == 0) {
        float ax = cor[2 * c], ay = cor[2 * c + 1];
        atomicAdd(out, m + fmaf(ax, ax, ay * ay));
    }
}

extern "C" void kernel_launch(void* const* d_in, const int* in_sizes, int n_in,
                              void* d_out, int out_size, void* d_ws, size_t ws_size,
                              hipStream_t stream) {
    const float* pnt   = (const float*)d_in[0];  // (400000,3)
    const float* cor   = (const float*)d_in[1];  // (128,2)
    const float* cam   = (const float*)d_in[2];  // (3,)
    const float* theta = (const float*)d_in[3];  // (3,)
    const float* vang  = (const float*)d_in[4];  // (1,)
    const int*   hh    = (const int*)d_in[5];    // scalar int
    const int*   ww    = (const int*)d_in[6];    // scalar int

    int n  = in_sizes[0] / 3;
    int NB = (n + TILE - 1) / TILE;

    float* scal  = (float*)d_ws;                     // 12 floats
    float* pbmin = (float*)((char*)d_ws + 256);      // NC * NB floats

    init_kernel<<<1, 64, 0, stream>>>(theta, vang, hh, ww, scal, (float*)d_out);
    proj_min_kernel<<<NB, BLOCK, 0, stream>>>(pnt, cor, cam, scal, pbmin, n, NB);
    reduce_kernel<<<NC, 64, 0, stream>>>(pbmin, cor, (float*)d_out, NB);
}